// Round 3
// baseline (425.665 us; speedup 1.0000x reference)
//
#include <hip/hip_runtime.h>
#include <hip/hip_bf16.h>

// Problem constants
#define TT    4352   // T = SEQ + 2*STATE
#define NBATCH 4
#define DD    64     // DK == DV
#define DIN_  512

typedef _Float16 h4 __attribute__((ext_vector_type(4)));
typedef _Float16 h8 __attribute__((ext_vector_type(8)));
typedef float    f4 __attribute__((ext_vector_type(4)));

static __device__ __forceinline__ h8 cat8(h4 lo, h4 hi) {
  return __builtin_shufflevector(lo, hi, 0, 1, 2, 3, 4, 5, 6, 7);
}

// ---------------------------------------------------------------------------
// Kernel 1: convert & transpose weights to fp16.
// WT[n][k] = W*(k, n&63) for n in [0,192): 0-63 Wq(*0.125), 64-127 Wk, 128-191 Wv
// blockIdx.x in [0,384): >=192 -> the _s set.
// ---------------------------------------------------------------------------
__global__ void prep_w_k(const float* __restrict__ Wq, const float* __restrict__ Wk,
                         const float* __restrict__ Wv, const float* __restrict__ Wqs,
                         const float* __restrict__ Wks, const float* __restrict__ Wvs,
                         _Float16* __restrict__ WT, _Float16* __restrict__ WTs) {
  const int n = blockIdx.x;      // 0..383
  const int k = threadIdx.x;     // 0..511
  const bool sflag = (n >= 192);
  const int nn = sflag ? n - 192 : n;
  const int m = nn >> 6;         // 0=q,1=k,2=v
  const int c = nn & 63;
  const float* src = sflag ? (m == 0 ? Wqs : (m == 1 ? Wks : Wvs))
                           : (m == 0 ? Wq  : (m == 1 ? Wk  : Wv));
  float v = src[k * DD + c];
  if (m == 0) v *= 0.125f;       // fold attention scale into Q projection
  (sflag ? WTs : WT)[nn * DIN_ + k] = (_Float16)v;
}

// ---------------------------------------------------------------------------
// Kernel 2: QKV projection via mfma_f32_16x16x32_f16.
// Block = 256 thr (4 waves), 64 consecutive global rows (never crosses batch
// or state-region boundaries: both are multiples of 64).
// Wave w owns rows [g0+16w, +16), all 192 output cols (12 n-tiles).
// Outputs: Q,K row-major fp16 [B*T][64]; V transposed VT[b][64][T] fp16.
// ---------------------------------------------------------------------------
__global__ __launch_bounds__(256) void qkv_proj_k(
    const float* __restrict__ x, const _Float16* __restrict__ WT,
    const _Float16* __restrict__ WTs, _Float16* __restrict__ Q,
    _Float16* __restrict__ K, _Float16* __restrict__ VT) {
  const int g0   = blockIdx.x * 64;       // global row base (b*T + t)
  const int tid  = threadIdx.x;
  const int wv   = tid >> 6;
  const int lane = tid & 63;
  const int l15  = lane & 15;
  const int g4   = lane >> 4;

  const int t0 = g0 % TT;
  const int bb = g0 / TT;
  const bool use_s = (t0 < 128) || (t0 >= 4224);
  const _Float16* __restrict__ W = use_s ? WTs : WT;

  const float* xp = x + (size_t)(g0 + wv * 16 + l15) * DIN_ + 4 * g4;

  f4 acc[12] = {};
  for (int ks = 0; ks < 16; ++ks) {
    f4 a0 = *(const f4*)(xp + 32 * ks);
    f4 a1 = *(const f4*)(xp + 32 * ks + 16);
    h8 af;
#pragma unroll
    for (int i = 0; i < 4; ++i) { af[i] = (_Float16)a0[i]; af[4 + i] = (_Float16)a1[i]; }
#pragma unroll
    for (int j = 0; j < 12; ++j) {
      const _Float16* wp = W + (size_t)(16 * j + l15) * DIN_ + 32 * ks + 4 * g4;
      h4 lo = *(const h4*)wp;
      h4 hi = *(const h4*)(wp + 16);
      acc[j] = __builtin_amdgcn_mfma_f32_16x16x32_f16(af, cat8(lo, hi), acc[j], 0, 0, 0);
    }
  }

  // D layout: lane holds D[row=4*g4+r][col=l15] of each 16x16 tile.
  const int orow0 = g0 + wv * 16 + 4 * g4;
#pragma unroll
  for (int j = 0; j < 4; ++j)
#pragma unroll
    for (int r = 0; r < 4; ++r)
      Q[(size_t)(orow0 + r) * DD + 16 * j + l15] = (_Float16)acc[j][r];
#pragma unroll
  for (int j = 4; j < 8; ++j)
#pragma unroll
    for (int r = 0; r < 4; ++r)
      K[(size_t)(orow0 + r) * DD + 16 * (j - 4) + l15] = (_Float16)acc[j][r];
#pragma unroll
  for (int j = 8; j < 12; ++j) {
    h4 pk;
#pragma unroll
    for (int r = 0; r < 4; ++r) pk[r] = (_Float16)acc[j][r];
    *(h4*)(VT + (size_t)(bb * DD + 16 * (j - 8) + l15) * TT + (t0 + wv * 16 + 4 * g4)) = pk;
  }
}

// ---------------------------------------------------------------------------
// Kernel 3: causal flash attention, all-register (K/V are L2-resident).
// Block = 256 thr (4 waves), q-tile = 64 rows, wave w owns 16 q-rows.
// Swapped MFMAs: S^T = mfma(Kfrag, Qfrag)  -> lane holds S[q=l15][kv=16j+4g4+r]
//                O^T = mfma(VTfrag, Pfrag) -> lane holds O[q=l15][d=16j+4g4+r]
// so softmax stats (per q-row l15) reduce with 2 shfl_xor and P feeds PV
// directly from registers.
// ---------------------------------------------------------------------------
__global__ __launch_bounds__(256) void attn_k(
    const _Float16* __restrict__ Q, const _Float16* __restrict__ K,
    const _Float16* __restrict__ VT, float* __restrict__ out) {
  const int bid  = blockIdx.x;
  const int qt   = 67 - (bid >> 2);   // heavy q-tiles dispatched first
  const int b    = bid & 3;
  const int q0   = qt * 64;
  const int tid  = threadIdx.x;
  const int wv   = tid >> 6;
  const int lane = tid & 63;
  const int l15  = lane & 15;
  const int g4   = lane >> 4;

  const int qrow = q0 + wv * 16 + l15;           // this lane's q row
  const _Float16* Qp = Q + (size_t)(b * TT + qrow) * DD + 4 * g4;
  const _Float16* Kb = K + (size_t)b * TT * DD;
  const _Float16* Vb = VT + (size_t)b * DD * TT;

  h8 qf[2];
#pragma unroll
  for (int ks = 0; ks < 2; ++ks) {
    h4 lo = *(const h4*)(Qp + 32 * ks);
    h4 hi = *(const h4*)(Qp + 32 * ks + 16);
    qf[ks] = cat8(lo, hi);
  }

  f4 o[4] = {};
  float mrow = -1e30f, lrow = 0.f;

  for (int kv0 = 0; kv0 <= q0; kv0 += 64) {
    // ---- S^T = K_tile . Q^T  (k-dim = d = 64, 2 ksteps) ----
    f4 s[4] = {};
#pragma unroll
    for (int j = 0; j < 4; ++j) {
      const _Float16* kp = Kb + (size_t)(kv0 + 16 * j + l15) * DD + 4 * g4;
#pragma unroll
      for (int ks = 0; ks < 2; ++ks) {
        h4 lo = *(const h4*)(kp + 32 * ks);
        h4 hi = *(const h4*)(kp + 32 * ks + 16);
        s[j] = __builtin_amdgcn_mfma_f32_16x16x32_f16(cat8(lo, hi), qf[ks], s[j], 0, 0, 0);
      }
    }
    // ---- causal mask (diagonal tile only) ----
    if (kv0 == q0) {
#pragma unroll
      for (int j = 0; j < 4; ++j)
#pragma unroll
        for (int r = 0; r < 4; ++r)
          if (kv0 + 16 * j + 4 * g4 + r > qrow) s[j][r] = -1e30f;
    }
    // ---- online softmax (per q-row = l15; reduce over 4 lane-groups) ----
    float tmax = s[0][0];
#pragma unroll
    for (int j = 0; j < 4; ++j)
#pragma unroll
      for (int r = 0; r < 4; ++r) tmax = fmaxf(tmax, s[j][r]);
    tmax = fmaxf(tmax, __shfl_xor(tmax, 16, 64));
    tmax = fmaxf(tmax, __shfl_xor(tmax, 32, 64));
    const float mnew = fmaxf(mrow, tmax);
    const float fsc = exp2f((mrow - mnew) * 1.44269504f);

    float psum = 0.f;
    h8 pa[2];
#pragma unroll
    for (int j = 0; j < 4; ++j)
#pragma unroll
      for (int r = 0; r < 4; ++r) {
        float p = exp2f((s[j][r] - mnew) * 1.44269504f);
        psum += p;
        pa[j >> 1][(j & 1) * 4 + r] = (_Float16)p;
      }
    psum += __shfl_xor(psum, 16, 64);
    psum += __shfl_xor(psum, 32, 64);
    lrow = lrow * fsc + psum;
    mrow = mnew;
#pragma unroll
    for (int j = 0; j < 4; ++j) {
      o[j][0] *= fsc; o[j][1] *= fsc; o[j][2] *= fsc; o[j][3] *= fsc;
    }
    // ---- O^T += V^T . P^T  (k-dim = kv = 64, 2 ksteps) ----
#pragma unroll
    for (int j = 0; j < 4; ++j) {
      const _Float16* vp = Vb + (size_t)(16 * j + l15) * TT + kv0 + 4 * g4;
#pragma unroll
      for (int ks = 0; ks < 2; ++ks) {
        h4 lo = *(const h4*)(vp + 32 * ks);
        h4 hi = *(const h4*)(vp + 32 * ks + 16);
        o[j] = __builtin_amdgcn_mfma_f32_16x16x32_f16(cat8(lo, hi), pa[ks], o[j], 0, 0, 0);
      }
    }
  }

  const float inv = 1.f / lrow;
  float* op = out + (size_t)(b * TT + qrow) * DD + 4 * g4;
#pragma unroll
  for (int j = 0; j < 4; ++j) {
    f4 res = { o[j][0] * inv, o[j][1] * inv, o[j][2] * inv, o[j][3] * inv };
    *(f4*)(op + 16 * j) = res;
  }
}

// ---------------------------------------------------------------------------
extern "C" void kernel_launch(void* const* d_in, const int* in_sizes, int n_in,
                              void* d_out, int out_size, void* d_ws, size_t ws_size,
                              hipStream_t stream) {
  const float* x   = (const float*)d_in[0];
  const float* Wq  = (const float*)d_in[1];
  const float* Wk  = (const float*)d_in[2];
  const float* Wv  = (const float*)d_in[3];
  const float* Wqs = (const float*)d_in[4];
  const float* Wks = (const float*)d_in[5];
  const float* Wvs = (const float*)d_in[6];
  float* out = (float*)d_out;

  char* ws = (char*)d_ws;
  const size_t WT_BYTES = (size_t)192 * DIN_ * sizeof(_Float16);   // 196608
  const size_t QK_BYTES = (size_t)NBATCH * TT * DD * sizeof(_Float16); // 2228224
  _Float16* WT  = (_Float16*)(ws);
  _Float16* WTs = (_Float16*)(ws + WT_BYTES);
  _Float16* Qh  = (_Float16*)(ws + 2 * WT_BYTES);
  _Float16* Kh  = (_Float16*)(ws + 2 * WT_BYTES + QK_BYTES);
  _Float16* VTh = (_Float16*)(ws + 2 * WT_BYTES + 2 * QK_BYTES);

  hipLaunchKernelGGL(prep_w_k, dim3(384), dim3(512), 0, stream,
                     Wq, Wk, Wv, Wqs, Wks, Wvs, WT, WTs);
  hipLaunchKernelGGL(qkv_proj_k, dim3(NBATCH * TT / 64), dim3(256), 0, stream,
                     x, WT, WTs, Qh, Kh, VTh);
  hipLaunchKernelGGL(attn_k, dim3(NBATCH * TT / 64), dim3(256), 0, stream,
                     Qh, Kh, VTh, out);
}

// Round 4
// 369.834 us; speedup vs baseline: 1.1510x; 1.1510x over previous
//
#include <hip/hip_runtime.h>
#include <hip/hip_bf16.h>

// Problem constants
#define TT    4352   // T = SEQ + 2*STATE
#define NBATCH 4
#define DD    64     // DK == DV
#define DIN_  512
#define NQT   68     // q-tiles (64 rows) per batch
#define NCH   5      // KV split factor per q-tile

typedef _Float16 h4 __attribute__((ext_vector_type(4)));
typedef _Float16 h8 __attribute__((ext_vector_type(8)));
typedef float    f4 __attribute__((ext_vector_type(4)));

static __device__ __forceinline__ h8 cat8(h4 lo, h4 hi) {
  return __builtin_shufflevector(lo, hi, 0, 1, 2, 3, 4, 5, 6, 7);
}

// ---------------------------------------------------------------------------
// Kernel 1: convert & transpose weights to fp16 (tiny, unchanged).
// ---------------------------------------------------------------------------
__global__ void prep_w_k(const float* __restrict__ Wq, const float* __restrict__ Wk,
                         const float* __restrict__ Wv, const float* __restrict__ Wqs,
                         const float* __restrict__ Wks, const float* __restrict__ Wvs,
                         _Float16* __restrict__ WT, _Float16* __restrict__ WTs) {
  const int n = blockIdx.x;      // 0..383
  const int k = threadIdx.x;     // 0..511
  const bool sflag = (n >= 192);
  const int nn = sflag ? n - 192 : n;
  const int m = nn >> 6;         // 0=q,1=k,2=v
  const int c = nn & 63;
  const float* src = sflag ? (m == 0 ? Wqs : (m == 1 ? Wks : Wvs))
                           : (m == 0 ? Wq  : (m == 1 ? Wk  : Wv));
  float v = src[k * DD + c];
  if (m == 0) v *= 0.125f;       // fold attention scale into Q projection
  (sflag ? WTs : WT)[nn * DIN_ + k] = (_Float16)v;
}

// ---------------------------------------------------------------------------
// Kernel 2: QKV projection. 768 threads = 12 waves: wave (rt, oid) with
// rt = wv&3 (16-row tile), oid = wv>>2 (0=Q,1=K,2=V). x-tile (64x512) is
// staged once into LDS as fp16 with an XOR swizzle (byte ^= (row&7)<<4 on
// 16B units) so ds_read_b64 column fragments are ~2-way conflict free.
// ---------------------------------------------------------------------------
__global__ __launch_bounds__(768) void qkv_proj_k(
    const float* __restrict__ x, const _Float16* __restrict__ WT,
    const _Float16* __restrict__ WTs, _Float16* __restrict__ Q,
    _Float16* __restrict__ K, _Float16* __restrict__ VT) {
  __shared__ char xs[65536];               // 64 rows x 1024B (512 fp16)
  const int g0 = blockIdx.x * 64;          // global row base (b*T + t)
  const int t0 = g0 % TT;
  const int bb = g0 / TT;
  const int tid = threadIdx.x;

  // ---- stage x -> LDS (fp16, swizzled). 4096 16B-units / 768 threads ----
  for (int u = tid; u < 4096; u += 768) {
    const int r = u >> 6, uu = u & 63;     // row, 16B-unit within row
    const f4* xp = (const f4*)(x + (size_t)(g0 + r) * DIN_ + uu * 8);
    f4 a0 = xp[0], a1 = xp[1];
    h8 v;
#pragma unroll
    for (int i = 0; i < 4; ++i) { v[i] = (_Float16)a0[i]; v[4 + i] = (_Float16)a1[i]; }
    *(h8*)(xs + r * 1024 + ((uu * 16) ^ ((r & 7) << 4))) = v;
  }
  __syncthreads();

  const int wv = tid >> 6, lane = tid & 63, l15 = lane & 15, g4 = lane >> 4;
  const int rt = wv & 3, oid = wv >> 2;
  const bool use_s = (t0 < 128) || (t0 >= 4224);
  const _Float16* __restrict__ W = (use_s ? WTs : WT) + (size_t)oid * 64 * DIN_;
  const int row = rt * 16 + l15;
  const int sxor = (row & 7) << 4;
  const char* xrow = xs + row * 1024;

  f4 acc[4] = {};
  for (int ks = 0; ks < 16; ++ks) {
    const int cb = (32 * ks + 4 * g4) * 2;
    h4 lo = *(const h4*)(xrow + (cb ^ sxor));
    h4 hi = *(const h4*)(xrow + ((cb + 32) ^ sxor));
    h8 af = cat8(lo, hi);
#pragma unroll
    for (int j = 0; j < 4; ++j) {
      const _Float16* wp = W + (size_t)(16 * j + l15) * DIN_ + 32 * ks + 4 * g4;
      h4 wlo = *(const h4*)wp;
      h4 whi = *(const h4*)(wp + 16);
      acc[j] = __builtin_amdgcn_mfma_f32_16x16x32_f16(af, cat8(wlo, whi), acc[j], 0, 0, 0);
    }
  }

  // D layout: lane holds D[row=4*g4+r][col=l15] per 16x16 tile.
  const int orow = g0 + rt * 16 + 4 * g4;
  if (oid == 0) {
#pragma unroll
    for (int j = 0; j < 4; ++j)
#pragma unroll
      for (int r = 0; r < 4; ++r)
        Q[(size_t)(orow + r) * DD + 16 * j + l15] = (_Float16)acc[j][r];
  } else if (oid == 1) {
#pragma unroll
    for (int j = 0; j < 4; ++j)
#pragma unroll
      for (int r = 0; r < 4; ++r)
        K[(size_t)(orow + r) * DD + 16 * j + l15] = (_Float16)acc[j][r];
  } else {
#pragma unroll
    for (int j = 0; j < 4; ++j) {
      h4 pk;
#pragma unroll
      for (int r = 0; r < 4; ++r) pk[r] = (_Float16)acc[j][r];
      *(h4*)(VT + (size_t)(bb * DD + 16 * j + l15) * TT + (t0 + rt * 16 + 4 * g4)) = pk;
    }
  }
}

// ---------------------------------------------------------------------------
// Kernel 3a: split-KV flash attention partials. Block = (b, qt, chunk c):
// chunk covers kv-tiles [c*sz, min(c*sz+sz, qt+1)), sz = ceil((qt+1)/NCH).
// Writes unnormalized O (f32) + per-row running max m and sum l.
// Swapped MFMAs as before; 4 waves x 16 q-rows.
// ---------------------------------------------------------------------------
__global__ __launch_bounds__(256, 8) void attn_part_k(
    const _Float16* __restrict__ Q, const _Float16* __restrict__ K,
    const _Float16* __restrict__ VT, float* __restrict__ Op,
    float* __restrict__ Mp, float* __restrict__ Lp) {
  const int bid = blockIdx.x;
  const int c  = bid % NCH;
  const int qt = NQT - 1 - ((bid / NCH) % NQT);  // heavy q-tiles first
  const int b  = bid / (NCH * NQT);
  const int n  = qt + 1;
  const int sz = (n + NCH - 1) / NCH;
  const int tb = c * sz;
  const int te = min(tb + sz, n);
  if (tb >= te) return;                          // empty chunk

  const int q0 = qt * 64;
  const int tid  = threadIdx.x;
  const int wv   = tid >> 6;
  const int lane = tid & 63;
  const int l15  = lane & 15;
  const int g4   = lane >> 4;

  const int qrow = q0 + wv * 16 + l15;
  const _Float16* Qp = Q + (size_t)(b * TT + qrow) * DD + 4 * g4;
  const _Float16* Kb = K + (size_t)b * TT * DD;
  const _Float16* Vb = VT + (size_t)b * DD * TT;

  h8 qf[2];
#pragma unroll
  for (int ks = 0; ks < 2; ++ks) {
    h4 lo = *(const h4*)(Qp + 32 * ks);
    h4 hi = *(const h4*)(Qp + 32 * ks + 16);
    qf[ks] = cat8(lo, hi);
  }

  f4 o[4] = {};
  float mrow = -1e30f, lrow = 0.f;

  for (int kv0 = tb * 64; kv0 < te * 64; kv0 += 64) {
    // ---- S^T = K_tile . Q^T ----
    f4 s[4] = {};
#pragma unroll
    for (int j = 0; j < 4; ++j) {
      const _Float16* kp = Kb + (size_t)(kv0 + 16 * j + l15) * DD + 4 * g4;
#pragma unroll
      for (int ks = 0; ks < 2; ++ks) {
        h4 lo = *(const h4*)(kp + 32 * ks);
        h4 hi = *(const h4*)(kp + 32 * ks + 16);
        s[j] = __builtin_amdgcn_mfma_f32_16x16x32_f16(cat8(lo, hi), qf[ks], s[j], 0, 0, 0);
      }
    }
    // ---- causal mask (diagonal tile only) ----
    if (kv0 == q0) {
#pragma unroll
      for (int j = 0; j < 4; ++j)
#pragma unroll
        for (int r = 0; r < 4; ++r)
          if (kv0 + 16 * j + 4 * g4 + r > qrow) s[j][r] = -1e30f;
    }
    // ---- online softmax (per q-row l15; reduce over 4 lane-groups) ----
    float tmax = s[0][0];
#pragma unroll
    for (int j = 0; j < 4; ++j)
#pragma unroll
      for (int r = 0; r < 4; ++r) tmax = fmaxf(tmax, s[j][r]);
    tmax = fmaxf(tmax, __shfl_xor(tmax, 16, 64));
    tmax = fmaxf(tmax, __shfl_xor(tmax, 32, 64));
    const float mnew = fmaxf(mrow, tmax);
    const float fsc = exp2f((mrow - mnew) * 1.44269504f);

    float psum = 0.f;
    h8 pa[2];
#pragma unroll
    for (int j = 0; j < 4; ++j)
#pragma unroll
      for (int r = 0; r < 4; ++r) {
        float p = exp2f((s[j][r] - mnew) * 1.44269504f);
        psum += p;
        pa[j >> 1][(j & 1) * 4 + r] = (_Float16)p;
      }
    psum += __shfl_xor(psum, 16, 64);
    psum += __shfl_xor(psum, 32, 64);
    lrow = lrow * fsc + psum;
    mrow = mnew;
#pragma unroll
    for (int j = 0; j < 4; ++j) {
      o[j][0] *= fsc; o[j][1] *= fsc; o[j][2] *= fsc; o[j][3] *= fsc;
    }
    // ---- O^T += V^T . P^T ----
#pragma unroll
    for (int j = 0; j < 4; ++j) {
      const _Float16* vp = Vb + (size_t)(16 * j + l15) * TT + kv0 + 4 * g4;
#pragma unroll
      for (int ks = 0; ks < 2; ++ks) {
        h4 lo = *(const h4*)(vp + 32 * ks);
        h4 hi = *(const h4*)(vp + 32 * ks + 16);
        o[j] = __builtin_amdgcn_mfma_f32_16x16x32_f16(cat8(lo, hi), pa[ks], o[j], 0, 0, 0);
      }
    }
  }

  // ---- write partials (unnormalized) ----
  const int pb = (b * NQT + qt) * NCH + c;
  float* op = Op + (size_t)pb * 4096 + (wv * 16 + l15) * 64 + 4 * g4;
#pragma unroll
  for (int j = 0; j < 4; ++j) *(f4*)(op + 16 * j) = o[j];
  if (g4 == 0) {
    Mp[pb * 64 + wv * 16 + l15] = mrow;
    Lp[pb * 64 + wv * 16 + l15] = lrow;
  }
}

// ---------------------------------------------------------------------------
// Kernel 3b: combine partials. Block = 4 rows x 64 lanes (d).
// ---------------------------------------------------------------------------
__global__ __launch_bounds__(256) void attn_comb_k(
    const float* __restrict__ Op, const float* __restrict__ Mp,
    const float* __restrict__ Lp, float* __restrict__ out) {
  const int g = blockIdx.x * 4 + (threadIdx.x >> 6);  // global row
  const int lane = threadIdx.x & 63;
  const int b = g / TT, t = g % TT;
  const int qt = t >> 6, r = t & 63;
  const int n = qt + 1, sz = (n + NCH - 1) / NCH;
  const int pb0 = (b * NQT + qt) * NCH;

  float m[NCH];
  float M = -1e30f;
  int nv = 0;
#pragma unroll
  for (int c = 0; c < NCH; ++c)
    if (c * sz < n) { m[c] = Mp[(pb0 + c) * 64 + r]; M = fmaxf(M, m[c]); nv = c + 1; }

  float L = 0.f, o = 0.f;
#pragma unroll
  for (int c = 0; c < NCH; ++c)
    if (c < nv) {
      const float w = exp2f((m[c] - M) * 1.44269504f);
      L += Lp[(pb0 + c) * 64 + r] * w;
      o += Op[(size_t)(pb0 + c) * 4096 + r * 64 + lane] * w;
    }
  out[(size_t)g * 64 + lane] = o / L;
}

// ---------------------------------------------------------------------------
extern "C" void kernel_launch(void* const* d_in, const int* in_sizes, int n_in,
                              void* d_out, int out_size, void* d_ws, size_t ws_size,
                              hipStream_t stream) {
  const float* x   = (const float*)d_in[0];
  const float* Wq  = (const float*)d_in[1];
  const float* Wk  = (const float*)d_in[2];
  const float* Wv  = (const float*)d_in[3];
  const float* Wqs = (const float*)d_in[4];
  const float* Wks = (const float*)d_in[5];
  const float* Wvs = (const float*)d_in[6];
  float* out = (float*)d_out;

  char* ws = (char*)d_ws;
  const size_t WT_BYTES = (size_t)192 * DIN_ * sizeof(_Float16);        // 196608
  const size_t QK_BYTES = (size_t)NBATCH * TT * DD * sizeof(_Float16);  // 2228224
  const size_t OP_BYTES = (size_t)NBATCH * NQT * NCH * 4096 * sizeof(float); // 22282240
  const size_t ML_BYTES = (size_t)NBATCH * NQT * NCH * 64 * sizeof(float);   // 348160
  _Float16* WT  = (_Float16*)(ws);
  _Float16* WTs = (_Float16*)(ws + WT_BYTES);
  _Float16* Qh  = (_Float16*)(ws + 2 * WT_BYTES);
  _Float16* Kh  = (_Float16*)(ws + 2 * WT_BYTES + QK_BYTES);
  _Float16* VTh = (_Float16*)(ws + 2 * WT_BYTES + 2 * QK_BYTES);
  float*    Op  = (float*)(ws + 2 * WT_BYTES + 3 * QK_BYTES);
  float*    Mp  = (float*)(ws + 2 * WT_BYTES + 3 * QK_BYTES + OP_BYTES);
  float*    Lp  = (float*)(ws + 2 * WT_BYTES + 3 * QK_BYTES + OP_BYTES + ML_BYTES);

  hipLaunchKernelGGL(prep_w_k, dim3(384), dim3(512), 0, stream,
                     Wq, Wk, Wv, Wqs, Wks, Wvs, WT, WTs);
  hipLaunchKernelGGL(qkv_proj_k, dim3(NBATCH * TT / 64), dim3(768), 0, stream,
                     x, WT, WTs, Qh, Kh, VTh);
  hipLaunchKernelGGL(attn_part_k, dim3(NBATCH * NQT * NCH), dim3(256), 0, stream,
                     Qh, Kh, VTh, Op, Mp, Lp);
  hipLaunchKernelGGL(attn_comb_k, dim3(NBATCH * TT / 4), dim3(256), 0, stream,
                     Op, Mp, Lp, out);
}